// Round 9
// baseline (262.919 us; speedup 1.0000x reference)
//
#include <hip/hip_runtime.h>
#include <hip/hip_bf16.h>

// B=4, T=2048, C=1024, H=16, Dh=64, M = B*T = 8192

typedef float f32x4 __attribute__((ext_vector_type(4)));
typedef __bf16 bf16x8 __attribute__((ext_vector_type(8)));

#define DEVI __device__ __forceinline__

// 0.125 (1/sqrt(Dh)) * log2(e): Q pre-scaled so softmax runs in base-2.
#define QSCALE 0.1803368801111204f

template<int N> struct IC { static constexpr int value = N; };

DEVI ushort f2b(float x) {
  __hip_bfloat16 h = __float2bfloat16(x);
  return __builtin_bit_cast(ushort, h);
}

DEVI unsigned int pkbf(float a, float b) {
#if __has_builtin(__builtin_amdgcn_cvt_pk_bf16_f32)
  typedef __bf16 bf16x2 __attribute__((ext_vector_type(2)));
  bf16x2 r = __builtin_amdgcn_cvt_pk_bf16_f32(a, b);
  return __builtin_bit_cast(unsigned int, r);
#else
  return (unsigned int)f2b(a) | ((unsigned int)f2b(b) << 16);
#endif
}

DEVI bf16x8 ldsFrag(const ushort* p) {
  return __builtin_bit_cast(bf16x8, *(const uint4*)p);
}

DEVI f32x4 mfma16(bf16x8 a, bf16x8 b, f32x4 c) {
  return __builtin_amdgcn_mfma_f32_16x16x32_bf16(a, b, c, 0, 0, 0);
}

DEVI void gload_lds16(const ushort* g, ushort* l) {
  __builtin_amdgcn_global_load_lds(
      (const __attribute__((address_space(1))) unsigned int*)g,
      (__attribute__((address_space(3))) unsigned int*)l, 16, 0, 0);
}

// ---------------- fp32 -> bf16 converts ----------------
__global__ void k_cvt(const float4* __restrict__ in, ushort4* __restrict__ out, int n4) {
  int i = blockIdx.x * 256 + threadIdx.x;
  if (i >= n4) return;
  float4 f = in[i];
  ushort4 o;
  o.x = f2b(f.x); o.y = f2b(f.y); o.z = f2b(f.z); o.w = f2b(f.w);
  out[i] = o;
}

__global__ void k_cvtW(const float4* __restrict__ w0, const float4* __restrict__ w1,
                       const float4* __restrict__ w2, const float4* __restrict__ w3,
                       ushort4* __restrict__ out) {
  const int y = blockIdx.y;
  const float4* src = (y == 0) ? w0 : (y == 1) ? w1 : (y == 2) ? w2 : w3;
  const int i = blockIdx.x * 256 + threadIdx.x;
  float4 f = src[i];
  ushort4 o;
  o.x = f2b(f.x); o.y = f2b(f.y); o.z = f2b(f.z); o.w = f2b(f.w);
  out[y * 262144 + i] = o;
}

// ---------------- GEMM: out = A[M,K] * W[N,K]^T + bias ----------------
// BK=64, XOR chunk swizzle (0 bank conflicts), LDS DOUBLE-BUFFERED:
// stage(next) issues before compute(cur) -> global_load_lds flies during the
// 32 MFMAs; one barrier per K-step. 1-D grid, XCD-swizzled.
// MODE 0: fused QKV (N=3072); MODE 1: out-proj fp32.
// Q/K and MODE1 use swapped-operand MFMA (computes C^T) for vectorized stores.
template<int MODE>
__global__ __launch_bounds__(256, 2)
void k_gemm(const ushort* __restrict__ A, const ushort* __restrict__ W,
            const float* __restrict__ b0, const float* __restrict__ b1,
            const float* __restrict__ b2, float* __restrict__ outF,
            ushort* __restrict__ oQ, ushort* __restrict__ oK, ushort* __restrict__ oV) {
  __shared__ ushort As[2 * 128 * 64];   // 32 KB
  __shared__ ushort Bs[2 * 128 * 64];   // 32 KB
  const int tid = threadIdx.x;
  const int wave = tid >> 6, lane = tid & 63;
  const int col = lane & 15, quad = lane >> 4;
  const int id = blockIdx.x;
  const int s_ = id >> 3;
  const int m0 = ((id & 7) * 8 + (s_ & 7)) * 128;   // 64 m-tiles, 8 per XCD
  const int n0 = (s_ >> 3) * 128;
  const int wm = (wave >> 1) * 64, wn = (wave & 1) * 64;
  f32x4 acc[4][4] = {};

  // staging: per gload g, this lane covers row g*32 + wave*8 + (lane>>3),
  // loading swizzled global chunk (lane&7)^(lane>>3).
  const int grow = lane >> 3;                 // 0..7
  const int gchunk = ((lane & 7) ^ grow) * 8; // swizzled k-offset (elements)
  const ushort* Ag = A + (size_t)(m0 + wave * 8 + grow) * 1024 + gchunk;
  const ushort* Wg = W + (size_t)(n0 + wave * 8 + grow) * 1024 + gchunk;

  const int matId = (MODE == 0) ? (n0 >> 10) : 0;
  const int cswz = col & 7;

  auto stage = [&](int buf, int k0) {
    ushort* aw = &As[buf * 8192 + wave * 512];
    ushort* bw = &Bs[buf * 8192 + wave * 512];
#pragma unroll
    for (int g = 0; g < 4; ++g) {
      gload_lds16(Ag + (size_t)g * 32 * 1024 + k0, aw + g * 2048);
      gload_lds16(Wg + (size_t)g * 32 * 1024 + k0, bw + g * 2048);
    }
  };

  auto kloop = [&](auto swc) {
    constexpr bool SW = (decltype(swc)::value != 0);
    stage(0, 0);
#pragma unroll 2
    for (int it = 0; it < 16; ++it) {
      const int buf = it & 1;
      __syncthreads();                       // buf's loads drained
      if (it + 1 < 16) stage(buf ^ 1, (it + 1) * 64);
      const ushort* Ab = &As[buf * 8192];
      const ushort* Bb = &Bs[buf * 8192];
#pragma unroll
      for (int kk = 0; kk < 2; ++kk) {
        bf16x8 af[4], bfr[4];
#pragma unroll
        for (int i = 0; i < 4; ++i)
          af[i] = ldsFrag(&Ab[(wm + i * 16 + col) * 64 + (((kk * 4 + quad) ^ cswz) * 8)]);
#pragma unroll
        for (int j = 0; j < 4; ++j)
          bfr[j] = ldsFrag(&Bb[(wn + j * 16 + col) * 64 + (((kk * 4 + quad) ^ cswz) * 8)]);
#pragma unroll
        for (int i = 0; i < 4; ++i)
#pragma unroll
          for (int j = 0; j < 4; ++j) {
            if constexpr (SW)
              acc[i][j] = mfma16(bfr[j], af[i], acc[i][j]);   // D = C^T tile
            else
              acc[i][j] = mfma16(af[i], bfr[j], acc[i][j]);
          }
      }
    }
  };

  if (MODE == 1 || matId < 2) kloop(IC<1>{}); else kloop(IC<0>{});

  if (MODE == 1) {
    // swapped: lane holds n = n0+wn+j*16+quad*4+r, m = m0+wm+i*16+col
#pragma unroll
    for (int j = 0; j < 4; ++j) {
      const int nb = n0 + wn + j * 16 + quad * 4;
      const float4 bb = *(const float4*)&b0[nb];
#pragma unroll
      for (int i = 0; i < 4; ++i) {
        const int m = m0 + wm + i * 16 + col;
        float4 v;
        v.x = acc[i][j][0] + bb.x;
        v.y = acc[i][j][1] + bb.y;
        v.z = acc[i][j][2] + bb.z;
        v.w = acc[i][j][3] + bb.w;
        *(float4*)&outF[(size_t)m * 1024 + nb] = v;
      }
    }
  } else if (matId < 2) {
    // swapped: lane holds 4 consecutive dh at fixed t -> 8B stores
    ushort* dst = (matId == 0) ? oQ : oK;
    const float* bias = (matId == 0) ? b0 : b1;
    const float sc = (matId == 0) ? QSCALE : 1.0f;
#pragma unroll
    for (int j = 0; j < 4; ++j) {
      const int nl = ((n0 & 1023) + wn + j * 16 + quad * 4);
      const int h = nl >> 6, dh0 = nl & 63;
      const float4 bb = *(const float4*)&bias[nl];
#pragma unroll
      for (int i = 0; i < 4; ++i) {
        const int m = m0 + wm + i * 16 + col;
        const int b = m >> 11, t = m & 2047;
        ushort4 pk;
        pk.x = f2b((acc[i][j][0] + bb.x) * sc);
        pk.y = f2b((acc[i][j][1] + bb.y) * sc);
        pk.z = f2b((acc[i][j][2] + bb.z) * sc);
        pk.w = f2b((acc[i][j][3] + bb.w) * sc);
        *(ushort4*)&dst[(((size_t)(b * 16 + h) * 2048) + t) * 64 + dh0] = pk;
      }
    }
  } else {
    // V transposed [B,H,Dh,T]: unswapped, 4 consecutive t per r
#pragma unroll
    for (int j = 0; j < 4; ++j) {
      const int nl = ((n0 & 1023) + wn + j * 16 + col);
      const int h = nl >> 6, dh = nl & 63;
      const float bn = b2[nl];
#pragma unroll
      for (int i = 0; i < 4; ++i) {
        const int mBase = m0 + wm + i * 16 + quad * 4;
        const int b = mBase >> 11, t = mBase & 2047;
        ushort4 pk;
        pk.x = f2b(acc[i][j][0] + bn);
        pk.y = f2b(acc[i][j][1] + bn);
        pk.z = f2b(acc[i][j][2] + bn);
        pk.w = f2b(acc[i][j][3] + bn);
        *(ushort4*)&oV[(((size_t)(b * 16 + h) * 64) + dh) * 2048 + t] = pk;
      }
    }
  }
}

// ---------------- Flash attention (causal, base-2, no-max softmax) ----------------
// Q (pre-scaled), K: [BH,T,64]; Vt: [BH,64,T]; AO: [M,1024] bf16.
// Grid 1024, one 128-q tile/block, 3 blocks/CU. XCD swizzle keeps 8 bh per XCD;
// t = g(tt) balances per-CU work. K/V LDS: 128-B rows + XOR chunk swizzle.
__global__ __launch_bounds__(256, 3)
void k_attn(const ushort* __restrict__ Q, const ushort* __restrict__ K,
            const ushort* __restrict__ Vt, ushort* __restrict__ AO) {
  __shared__ ushort Ks[2 * 4096];         // [buf][kv 64][dh 64]
  __shared__ ushort Vs[2 * 4096];         // [buf][dh 64][kv 64]
  __shared__ ushort Os[512];              // ones A-tile: row0 = 1.0, rest 0
  __shared__ ushort Ps[4 * 2 * 16 * 72];  // [wave][strip][q 16][kv 64 + pad]
  const int tid = threadIdx.x;
  const int wave = tid >> 6, lane = tid & 63;
  const int col = lane & 15, quad = lane >> 4;
  const int id = blockIdx.x;
  const int bh = (id & 7) * 8 + ((id >> 3) & 7);
  const int tt = id >> 6;                 // 0..15
  const int hi = tt >> 2, lo = tt & 3;
  const int t = (hi & 1) ? (15 - (hi >> 1) - 2 * lo) : ((hi >> 1) + 2 * lo);
  const int q0 = t * 128;
  const ushort* Qg = Q + (size_t)bh * 2048 * 64;
  const ushort* Kg = K + (size_t)bh * 2048 * 64;
  const ushort* Vg = Vt + (size_t)bh * 64 * 2048;

  // init ones tile (A-operand: row0 = 1.0 across all k)
  if (tid < 128) {
    const ushort one = 0x3F80;
    ushort4 zv;
    if (tid < 8) { zv.x = one; zv.y = one; zv.z = one; zv.w = one; }
    else         { zv.x = 0;   zv.y = 0;   zv.z = 0;   zv.w = 0;   }
    *(ushort4*)&Os[tid * 4] = zv;
  }

  // Q B-frags for both strips
  bf16x8 qf[2][2];
#pragma unroll
  for (int s = 0; s < 2; ++s) {
    const ushort* p = Qg + (q0 + wave * 32 + s * 16 + col) * 64 + quad * 8;
    qf[s][0] = __builtin_bit_cast(bf16x8, *(const uint4*)p);
    qf[s][1] = __builtin_bit_cast(bf16x8, *(const uint4*)(p + 32));
  }

  f32x4 o[2][4] = {};
  f32x4 la[2] = {};

  const int grow = lane >> 3;
  const int gchunk = ((lane & 7) ^ grow) * 8;
  const ushort* kPtr = Kg + (wave * 8 + grow) * 64 + gchunk;
  const ushort* vPtr = Vg + (size_t)(wave * 8 + grow) * 2048 + gchunk;
  ushort* Pw0 = &Ps[((wave * 2 + 0) * 16 + col) * 72];
  ushort* Pw1 = &Ps[((wave * 2 + 1) * 16 + col) * 72];
  const int cswz = col & 7;

  auto stage = [&](auto bufc) {
    constexpr int BUF = decltype(bufc)::value;
    ushort* kb = &Ks[BUF * 4096 + wave * 512];
    ushort* vb = &Vs[BUF * 4096 + wave * 512];
    gload_lds16(kPtr,             kb);
    gload_lds16(kPtr + 32 * 64,   kb + 2048);
    gload_lds16(vPtr,             vb);
    gload_lds16(vPtr + 32 * 2048, vb + 2048);
    kPtr += 64 * 64;
    vPtr += 64;
  };

  auto step = [&](auto bufc, auto maskc, int j0) {
    constexpr int BUF = decltype(bufc)::value;
    constexpr bool MASKED = (decltype(maskc)::value != 0);
    const ushort* Kb = &Ks[BUF * 4096];
    const ushort* Vb = &Vs[BUF * 4096];
    bf16x8 kf[4][2];
#pragma unroll
    for (int i = 0; i < 4; ++i) {
      kf[i][0] = ldsFrag(&Kb[(i * 16 + col) * 64 + (((0 * 4 + quad) ^ cswz) * 8)]);
      kf[i][1] = ldsFrag(&Kb[(i * 16 + col) * 64 + (((1 * 4 + quad) ^ cswz) * 8)]);
    }
#pragma unroll
    for (int s = 0; s < 2; ++s) {
      ushort* Pw = s ? Pw1 : Pw0;
      const int dlim = MASKED ? (q0 + wave * 32 + s * 16 + col - j0 - quad * 4) : 0;
#pragma unroll
      for (int i = 0; i < 4; ++i) {
        f32x4 z = {0.f, 0.f, 0.f, 0.f};
        f32x4 sv = mfma16(kf[i][0], qf[s][0], z);
        sv = mfma16(kf[i][1], qf[s][1], sv);
        if (MASKED) {
#pragma unroll
          for (int r = 0; r < 4; ++r)
            if (i * 16 + r > dlim) sv[r] = -1e30f;
        }
        f32x4 pv;
#pragma unroll
        for (int r = 0; r < 4; ++r) pv[r] = __builtin_amdgcn_exp2f(sv[r]);
        uint2 pk;
        pk.x = pkbf(pv[0], pv[1]);
        pk.y = pkbf(pv[2], pv[3]);
        *(uint2*)&Pw[i * 16 + quad * 4] = pk;
      }
    }
    // PV: O^T[dh][q] += Vt * P^T ; l via ones-row MFMA
    bf16x8 osf = ldsFrag(&Os[col * 32 + quad * 8]);
#pragma unroll
    for (int c = 0; c < 2; ++c) {
      bf16x8 pb0 = ldsFrag(&Pw0[c * 32 + quad * 8]);
      bf16x8 pb1 = ldsFrag(&Pw1[c * 32 + quad * 8]);
      la[0] = mfma16(osf, pb0, la[0]);
      la[1] = mfma16(osf, pb1, la[1]);
#pragma unroll
      for (int i = 0; i < 4; ++i) {
        bf16x8 vf = ldsFrag(&Vb[(i * 16 + col) * 64 + (((c * 4 + quad) ^ cswz) * 8)]);
        o[0][i] = mfma16(vf, pb0, o[0][i]);
        o[1][i] = mfma16(vf, pb1, o[1][i]);
      }
    }
  };

  __syncthreads();                 // Os init visible
  stage(IC<0>{});                  // kv tile 0
  for (int it2 = 0; it2 < t; ++it2) {
    __syncthreads();
    stage(IC<1>{});
    step(IC<0>{}, IC<0>{}, 0);
    __syncthreads();
    stage(IC<0>{});
    step(IC<1>{}, IC<0>{}, 0);
  }
  __syncthreads();
  stage(IC<1>{});                  // diag tile B
  step(IC<0>{}, IC<1>{}, q0);      // diag tile A
  __syncthreads();
  step(IC<1>{}, IC<1>{}, q0 + 64); // diag tile B

  // epilogue: O^T C-layout: row dh = i*16 + quad*4 + r, col q = col
  const float invs[2] = {1.0f / __shfl(la[0][0], col), 1.0f / __shfl(la[1][0], col)};
  const int b = bh >> 4, h = bh & 15;
#pragma unroll
  for (int s = 0; s < 2; ++s) {
    const float inv = invs[s];
    const int tq = q0 + wave * 32 + s * 16 + col;
    ushort* dst = AO + (size_t)(b * 2048 + tq) * 1024 + h * 64;
#pragma unroll
    for (int i = 0; i < 4; ++i) {
      f32x4 v = o[s][i];
      ushort4 pk;
      pk.x = f2b(v[0] * inv);
      pk.y = f2b(v[1] * inv);
      pk.z = f2b(v[2] * inv);
      pk.w = f2b(v[3] * inv);
      *(ushort4*)&dst[i * 16 + quad * 4] = pk;
    }
  }
}

// ---------------- launch ----------------
extern "C" void kernel_launch(void* const* d_in, const int* in_sizes, int n_in,
                              void* d_out, int out_size, void* d_ws, size_t ws_size,
                              hipStream_t stream) {
  const float* x  = (const float*)d_in[0];
  const float* Wq = (const float*)d_in[1];
  const float* bq = (const float*)d_in[2];
  const float* Wk = (const float*)d_in[3];
  const float* bk = (const float*)d_in[4];
  const float* Wv = (const float*)d_in[5];
  const float* bv = (const float*)d_in[6];
  const float* Wo = (const float*)d_in[7];
  const float* bo = (const float*)d_in[8];
  float* out = (float*)d_out;

  char* ws = (char*)d_ws;
  ushort* xb    = (ushort*)ws;                                 // 16 MB
  ushort* Wcat  = (ushort*)(ws + (size_t)16 * 1024 * 1024);    // 8 MB (Wq|Wk|Wv|Wo)
  ushort* Wob   = Wcat + (size_t)3 * 1024 * 1024;
  ushort* Qh    = (ushort*)(ws + (size_t)24 * 1024 * 1024);    // 16 MB
  ushort* Kh    = Qh + (size_t)8192 * 1024;
  ushort* Vt    = Kh + (size_t)8192 * 1024;
  ushort* AO    = Vt + (size_t)8192 * 1024;

  k_cvt<<<8192, 256, 0, stream>>>((const float4*)x, (ushort4*)xb, 8192 * 1024 / 4);
  k_cvtW<<<dim3(1024, 4), 256, 0, stream>>>((const float4*)Wq, (const float4*)Wk,
                                            (const float4*)Wv, (const float4*)Wo,
                                            (ushort4*)Wcat);

  // fused QKV GEMM: N = 3072, 1-D swizzled grid
  k_gemm<0><<<1536, 256, 0, stream>>>(xb, Wcat, bq, bk, bv, nullptr, Qh, Kh, Vt);

  k_attn<<<1024, 256, 0, stream>>>(Qh, Kh, Vt, AO);

  // out-projection: N = 1024, fp32 out
  k_gemm<1><<<512, 256, 0, stream>>>(AO, Wob, bo, nullptr, nullptr, out,
                                     nullptr, nullptr, nullptr);
}

// Round 10
// 248.987 us; speedup vs baseline: 1.0560x; 1.0560x over previous
//
#include <hip/hip_runtime.h>
#include <hip/hip_bf16.h>

// B=4, T=2048, C=1024, H=16, Dh=64, M = B*T = 8192

typedef float f32x4 __attribute__((ext_vector_type(4)));
typedef __bf16 bf16x8 __attribute__((ext_vector_type(8)));

#define DEVI __device__ __forceinline__

// 0.125 (1/sqrt(Dh)) * log2(e): Q pre-scaled so softmax runs in base-2.
#define QSCALE 0.1803368801111204f

template<int N> struct IC { static constexpr int value = N; };

DEVI ushort f2b(float x) {
  __hip_bfloat16 h = __float2bfloat16(x);
  return __builtin_bit_cast(ushort, h);
}

DEVI unsigned int pkbf(float a, float b) {
#if __has_builtin(__builtin_amdgcn_cvt_pk_bf16_f32)
  typedef __bf16 bf16x2 __attribute__((ext_vector_type(2)));
  bf16x2 r = __builtin_amdgcn_cvt_pk_bf16_f32(a, b);
  return __builtin_bit_cast(unsigned int, r);
#else
  return (unsigned int)f2b(a) | ((unsigned int)f2b(b) << 16);
#endif
}

DEVI bf16x8 ldsFrag(const ushort* p) {
  return __builtin_bit_cast(bf16x8, *(const uint4*)p);
}

DEVI f32x4 mfma16(bf16x8 a, bf16x8 b, f32x4 c) {
  return __builtin_amdgcn_mfma_f32_16x16x32_bf16(a, b, c, 0, 0, 0);
}

DEVI void gload_lds16(const ushort* g, ushort* l) {
  __builtin_amdgcn_global_load_lds(
      (const __attribute__((address_space(1))) unsigned int*)g,
      (__attribute__((address_space(3))) unsigned int*)l, 16, 0, 0);
}

// ---------------- fused fp32 -> bf16 convert (x + 4 weights) ----------------
__global__ void k_cvtAll(const float4* __restrict__ x,
                         const float4* __restrict__ w0, const float4* __restrict__ w1,
                         const float4* __restrict__ w2, const float4* __restrict__ w3,
                         ushort4* __restrict__ xb, ushort4* __restrict__ wcat) {
  const int blk = blockIdx.x;
  const int i = blk * 256 + threadIdx.x;
  float4 f;
  ushort4* dst;
  int di;
  if (blk < 8192) {                 // x: 2M float4
    f = x[i]; dst = xb; di = i;
  } else {                          // weights: 1M float4, 262144 per matrix
    const int wi = i - 8192 * 256;
    const int sel = wi >> 18;       // block-uniform (1024 blocks per W)
    const float4* src = (sel == 0) ? w0 : (sel == 1) ? w1 : (sel == 2) ? w2 : w3;
    f = src[wi & 262143]; dst = wcat; di = wi;
  }
  ushort4 o;
  o.x = f2b(f.x); o.y = f2b(f.y); o.z = f2b(f.z); o.w = f2b(f.w);
  dst[di] = o;
}

// ---------------- GEMM: out = A[M,K] * W[N,K]^T + bias ----------------
// R8 version (known-good 73.5us): BK=64, XOR chunk swizzle (0 conflicts),
// single-buffered. 1-D grid, XCD-swizzled.
// MODE 0: fused QKV (N=3072); MODE 1: out-proj fp32.
// Q/K and MODE1 use swapped-operand MFMA (computes C^T) for vectorized stores.
template<int MODE>
__global__ __launch_bounds__(256)
void k_gemm(const ushort* __restrict__ A, const ushort* __restrict__ W,
            const float* __restrict__ b0, const float* __restrict__ b1,
            const float* __restrict__ b2, float* __restrict__ outF,
            ushort* __restrict__ oQ, ushort* __restrict__ oK, ushort* __restrict__ oV) {
  __shared__ ushort As[128 * 64];   // 16 KB
  __shared__ ushort Bs[128 * 64];   // 16 KB
  const int tid = threadIdx.x;
  const int wave = tid >> 6, lane = tid & 63;
  const int col = lane & 15, quad = lane >> 4;
  const int id = blockIdx.x;
  const int s_ = id >> 3;
  const int m0 = ((id & 7) * 8 + (s_ & 7)) * 128;   // 64 m-tiles, 8 per XCD
  const int n0 = (s_ >> 3) * 128;
  const int wm = (wave >> 1) * 64, wn = (wave & 1) * 64;
  f32x4 acc[4][4] = {};

  const int grow = lane >> 3;                 // 0..7
  const int gchunk = ((lane & 7) ^ grow) * 8; // swizzled k-offset (elements)
  const ushort* Ag = A + (size_t)(m0 + wave * 8 + grow) * 1024 + gchunk;
  const ushort* Wg = W + (size_t)(n0 + wave * 8 + grow) * 1024 + gchunk;
  ushort* AsW = &As[wave * 512];
  ushort* BsW = &Bs[wave * 512];

  const int matId = (MODE == 0) ? (n0 >> 10) : 0;
  const int cswz = col & 7;

  auto kloop = [&](auto swc) {
    constexpr bool SW = (decltype(swc)::value != 0);
    for (int k0 = 0; k0 < 1024; k0 += 64) {
      __syncthreads();
#pragma unroll
      for (int g = 0; g < 4; ++g) {
        gload_lds16(Ag + (size_t)g * 32 * 1024 + k0, AsW + g * 2048);
        gload_lds16(Wg + (size_t)g * 32 * 1024 + k0, BsW + g * 2048);
      }
      __syncthreads();
#pragma unroll
      for (int kk = 0; kk < 2; ++kk) {
        bf16x8 af[4], bfr[4];
#pragma unroll
        for (int i = 0; i < 4; ++i)
          af[i] = ldsFrag(&As[(wm + i * 16 + col) * 64 + (((kk * 4 + quad) ^ cswz) * 8)]);
#pragma unroll
        for (int j = 0; j < 4; ++j)
          bfr[j] = ldsFrag(&Bs[(wn + j * 16 + col) * 64 + (((kk * 4 + quad) ^ cswz) * 8)]);
#pragma unroll
        for (int i = 0; i < 4; ++i)
#pragma unroll
          for (int j = 0; j < 4; ++j) {
            if constexpr (SW)
              acc[i][j] = mfma16(bfr[j], af[i], acc[i][j]);   // D = C^T tile
            else
              acc[i][j] = mfma16(af[i], bfr[j], acc[i][j]);
          }
      }
    }
  };

  if (MODE == 1 || matId < 2) kloop(IC<1>{}); else kloop(IC<0>{});

  if (MODE == 1) {
    // swapped: lane holds n = n0+wn+j*16+quad*4+r, m = m0+wm+i*16+col
#pragma unroll
    for (int j = 0; j < 4; ++j) {
      const int nb = n0 + wn + j * 16 + quad * 4;
      const float4 bb = *(const float4*)&b0[nb];
#pragma unroll
      for (int i = 0; i < 4; ++i) {
        const int m = m0 + wm + i * 16 + col;
        float4 v;
        v.x = acc[i][j][0] + bb.x;
        v.y = acc[i][j][1] + bb.y;
        v.z = acc[i][j][2] + bb.z;
        v.w = acc[i][j][3] + bb.w;
        *(float4*)&outF[(size_t)m * 1024 + nb] = v;
      }
    }
  } else if (matId < 2) {
    // swapped: lane holds 4 consecutive dh at fixed t -> 8B stores
    ushort* dst = (matId == 0) ? oQ : oK;
    const float* bias = (matId == 0) ? b0 : b1;
    const float sc = (matId == 0) ? QSCALE : 1.0f;
#pragma unroll
    for (int j = 0; j < 4; ++j) {
      const int nl = ((n0 & 1023) + wn + j * 16 + quad * 4);
      const int h = nl >> 6, dh0 = nl & 63;
      const float4 bb = *(const float4*)&bias[nl];
#pragma unroll
      for (int i = 0; i < 4; ++i) {
        const int m = m0 + wm + i * 16 + col;
        const int b = m >> 11, t = m & 2047;
        ushort4 pk;
        pk.x = f2b((acc[i][j][0] + bb.x) * sc);
        pk.y = f2b((acc[i][j][1] + bb.y) * sc);
        pk.z = f2b((acc[i][j][2] + bb.z) * sc);
        pk.w = f2b((acc[i][j][3] + bb.w) * sc);
        *(ushort4*)&dst[(((size_t)(b * 16 + h) * 2048) + t) * 64 + dh0] = pk;
      }
    }
  } else {
    // V transposed [B,H,Dh,T]: unswapped, 4 consecutive t per r
#pragma unroll
    for (int j = 0; j < 4; ++j) {
      const int nl = ((n0 & 1023) + wn + j * 16 + col);
      const int h = nl >> 6, dh = nl & 63;
      const float bn = b2[nl];
#pragma unroll
      for (int i = 0; i < 4; ++i) {
        const int mBase = m0 + wm + i * 16 + quad * 4;
        const int b = mBase >> 11, t = mBase & 2047;
        ushort4 pk;
        pk.x = f2b(acc[i][j][0] + bn);
        pk.y = f2b(acc[i][j][1] + bn);
        pk.z = f2b(acc[i][j][2] + bn);
        pk.w = f2b(acc[i][j][3] + bn);
        *(ushort4*)&oV[(((size_t)(b * 16 + h) * 64) + dh) * 2048 + t] = pk;
      }
    }
  }
}

// ---------------- Flash attention (causal, base-2, no-max softmax) ----------------
// Q (pre-scaled), K: [BH,T,64]; Vt: [BH,64,T]; AO: [M,1024] bf16.
// 512 threads (8 waves), 256 q-rows/block: same 16 KB K/V staging per kv-tile
// now feeds 8 waves -> 2x compute per barrier. Grid 256 (1 block/CU, 2 w/SIMD).
// Pairing t and 7-t -> exactly 36 kv-tile units per block. 4 peeled diagonal
// tiles with wave-uniform skip (wave < 2d fully above diagonal).
__global__ __launch_bounds__(512, 1)
void k_attn(const ushort* __restrict__ Q, const ushort* __restrict__ K,
            const ushort* __restrict__ Vt, ushort* __restrict__ AO) {
  __shared__ ushort Ks[2 * 4096];          // [buf][kv 64][dh 64]
  __shared__ ushort Vs[2 * 4096];          // [buf][dh 64][kv 64]
  __shared__ ushort Os[512];               // ones A-tile: row0 = 1.0, rest 0
  __shared__ ushort Ps[16 * 16 * 72];      // [strip 16][q 16][kv 64 + pad]
  const int tid = threadIdx.x;
  const int wave = tid >> 6, lane = tid & 63;
  const int col = lane & 15, quad = lane >> 4;
  const int id = blockIdx.x;
  const int bh = (id & 7) * 8 + ((id >> 3) & 7);
  const int pr = id >> 6;                  // 0..3
  const ushort* Qg = Q + (size_t)bh * 2048 * 64;
  const ushort* Kg = K + (size_t)bh * 2048 * 64;
  const ushort* Vg = Vt + (size_t)bh * 64 * 2048;

  // init ones tile (A-operand: row0 = 1.0 across all k)
  if (tid < 128) {
    const ushort one = 0x3F80;
    ushort4 zv;
    if (tid < 8) { zv.x = one; zv.y = one; zv.z = one; zv.w = one; }
    else         { zv.x = 0;   zv.y = 0;   zv.z = 0;   zv.w = 0;   }
    *(ushort4*)&Os[tid * 4] = zv;
  }

  const int grow = lane >> 3;
  const int gchunk = ((lane & 7) ^ grow) * 8;
  const int cswz = col & 7;
  ushort* Pw0 = &Ps[((wave * 2 + 0) * 16 + col) * 72];
  ushort* Pw1 = &Ps[((wave * 2 + 1) * 16 + col) * 72];

  for (int pp = 0; pp < 2; ++pp) {
    const int t = pp ? (7 - pr) : pr;      // 256-q tile index, 0..7
    const int q0 = t * 256;

    // Q B-frags for this wave's two strips
    bf16x8 qf[2][2];
#pragma unroll
    for (int s = 0; s < 2; ++s) {
      const ushort* p = Qg + (q0 + wave * 32 + s * 16 + col) * 64 + quad * 8;
      qf[s][0] = __builtin_bit_cast(bf16x8, *(const uint4*)p);
      qf[s][1] = __builtin_bit_cast(bf16x8, *(const uint4*)(p + 32));
    }

    f32x4 o[2][4] = {};
    f32x4 la[2] = {};

    const ushort* kPtr = Kg + (wave * 8 + grow) * 64 + gchunk;
    const ushort* vPtr = Vg + (size_t)(wave * 8 + grow) * 2048 + gchunk;

    auto stage = [&](auto bufc) {
      constexpr int BUF = decltype(bufc)::value;
      gload_lds16(kPtr, &Ks[BUF * 4096 + wave * 512]);
      gload_lds16(vPtr, &Vs[BUF * 4096 + wave * 512]);
      kPtr += 64 * 64;
      vPtr += 64;
    };

    auto step = [&](auto bufc, auto maskc, int j0) {
      constexpr int BUF = decltype(bufc)::value;
      constexpr bool MASKED = (decltype(maskc)::value != 0);
      const ushort* Kb = &Ks[BUF * 4096];
      const ushort* Vb = &Vs[BUF * 4096];
      bf16x8 kf[4][2];
#pragma unroll
      for (int i = 0; i < 4; ++i) {
        kf[i][0] = ldsFrag(&Kb[(i * 16 + col) * 64 + (((0 * 4 + quad) ^ cswz) * 8)]);
        kf[i][1] = ldsFrag(&Kb[(i * 16 + col) * 64 + (((1 * 4 + quad) ^ cswz) * 8)]);
      }
#pragma unroll
      for (int s = 0; s < 2; ++s) {
        ushort* Pw = s ? Pw1 : Pw0;
        const int dlim = MASKED ? (q0 + wave * 32 + s * 16 + col - j0 - quad * 4) : 0;
#pragma unroll
        for (int i = 0; i < 4; ++i) {
          f32x4 z = {0.f, 0.f, 0.f, 0.f};
          f32x4 sv = mfma16(kf[i][0], qf[s][0], z);
          sv = mfma16(kf[i][1], qf[s][1], sv);
          if (MASKED) {
#pragma unroll
            for (int r = 0; r < 4; ++r)
              if (i * 16 + r > dlim) sv[r] = -1e30f;
          }
          f32x4 pv;
#pragma unroll
          for (int r = 0; r < 4; ++r) pv[r] = __builtin_amdgcn_exp2f(sv[r]);
          uint2 pk;
          pk.x = pkbf(pv[0], pv[1]);
          pk.y = pkbf(pv[2], pv[3]);
          *(uint2*)&Pw[i * 16 + quad * 4] = pk;
        }
      }
      // PV: O^T[dh][q] += Vt * P^T ; l via ones-row MFMA
      bf16x8 osf = ldsFrag(&Os[col * 32 + quad * 8]);
#pragma unroll
      for (int c = 0; c < 2; ++c) {
        bf16x8 pb0 = ldsFrag(&Pw0[c * 32 + quad * 8]);
        bf16x8 pb1 = ldsFrag(&Pw1[c * 32 + quad * 8]);
        la[0] = mfma16(osf, pb0, la[0]);
        la[1] = mfma16(osf, pb1, la[1]);
#pragma unroll
        for (int i = 0; i < 4; ++i) {
          bf16x8 vf = ldsFrag(&Vb[(i * 16 + col) * 64 + (((c * 4 + quad) ^ cswz) * 8)]);
          o[0][i] = mfma16(vf, pb0, o[0][i]);
          o[1][i] = mfma16(vf, pb1, o[1][i]);
        }
      }
    };

    __syncthreads();                 // Os init / prior pass readers done
    stage(IC<0>{});                  // kv tile 0
    for (int it2 = 0; it2 < 2 * t; ++it2) {   // 4t full tiles
      __syncthreads();
      stage(IC<1>{});
      step(IC<0>{}, IC<0>{}, 0);
      __syncthreads();
      stage(IC<0>{});
      step(IC<1>{}, IC<0>{}, 0);
    }
    // 4 diagonal tiles (kv = q0 .. q0+256), parities 0,1,0,1
    __syncthreads();
    stage(IC<1>{});
    step(IC<0>{}, IC<1>{}, q0);
    __syncthreads();
    stage(IC<0>{});
    if (wave >= 2) step(IC<1>{}, IC<1>{}, q0 + 64);
    __syncthreads();
    stage(IC<1>{});
    if (wave >= 4) step(IC<0>{}, IC<1>{}, q0 + 128);
    __syncthreads();
    if (wave >= 6) step(IC<1>{}, IC<1>{}, q0 + 192);

    // epilogue: O^T C-layout: row dh = i*16 + quad*4 + r, col q = col
    const float invs[2] = {1.0f / __shfl(la[0][0], col), 1.0f / __shfl(la[1][0], col)};
    const int b = bh >> 4, h = bh & 15;
#pragma unroll
    for (int s = 0; s < 2; ++s) {
      const float inv = invs[s];
      const int tq = q0 + wave * 32 + s * 16 + col;
      ushort* dst = AO + (size_t)(b * 2048 + tq) * 1024 + h * 64;
#pragma unroll
      for (int i = 0; i < 4; ++i) {
        f32x4 v = o[s][i];
        ushort4 pk;
        pk.x = f2b(v[0] * inv);
        pk.y = f2b(v[1] * inv);
        pk.z = f2b(v[2] * inv);
        pk.w = f2b(v[3] * inv);
        *(ushort4*)&dst[i * 16 + quad * 4] = pk;
      }
    }
  }
}

// ---------------- launch ----------------
extern "C" void kernel_launch(void* const* d_in, const int* in_sizes, int n_in,
                              void* d_out, int out_size, void* d_ws, size_t ws_size,
                              hipStream_t stream) {
  const float* x  = (const float*)d_in[0];
  const float* Wq = (const float*)d_in[1];
  const float* bq = (const float*)d_in[2];
  const float* Wk = (const float*)d_in[3];
  const float* bk = (const float*)d_in[4];
  const float* Wv = (const float*)d_in[5];
  const float* bv = (const float*)d_in[6];
  const float* Wo = (const float*)d_in[7];
  const float* bo = (const float*)d_in[8];
  float* out = (float*)d_out;

  char* ws = (char*)d_ws;
  ushort* xb    = (ushort*)ws;                                 // 16 MB
  ushort* Wcat  = (ushort*)(ws + (size_t)16 * 1024 * 1024);    // 8 MB (Wq|Wk|Wv|Wo)
  ushort* Wob   = Wcat + (size_t)3 * 1024 * 1024;
  ushort* Qh    = (ushort*)(ws + (size_t)24 * 1024 * 1024);    // 16 MB
  ushort* Kh    = Qh + (size_t)8192 * 1024;
  ushort* Vt    = Kh + (size_t)8192 * 1024;
  ushort* AO    = Vt + (size_t)8192 * 1024;

  // fused converts: x (8192 blocks) + 4 weights (4096 blocks)
  k_cvtAll<<<12288, 256, 0, stream>>>((const float4*)x,
                                      (const float4*)Wq, (const float4*)Wk,
                                      (const float4*)Wv, (const float4*)Wo,
                                      (ushort4*)xb, (ushort4*)Wcat);

  // fused QKV GEMM: N = 3072, 1-D swizzled grid
  k_gemm<0><<<1536, 256, 0, stream>>>(xb, Wcat, bq, bk, bv, nullptr, Qh, Kh, Vt);

  k_attn<<<256, 512, 0, stream>>>(Qh, Kh, Vt, AO);

  // out-projection: N = 1024, fp32 out
  k_gemm<1><<<512, 256, 0, stream>>>(AO, Wob, bo, nullptr, nullptr, out,
                                     nullptr, nullptr, nullptr);
}